// Round 7
// baseline (51.197 us; speedup 1.0000x reference)
//
#include <hip/hip_runtime.h>
#include <hip/hip_bf16.h>

// Problem constants
#define BB   4
#define HH   32
#define QQ   16
#define NN   4096
#define HKV  8
#define DD   128
#define NK   3072
#define GRP  4

typedef __attribute__((ext_vector_type(8))) short bf16x8;
typedef __attribute__((ext_vector_type(4))) float f32x4;

__device__ __forceinline__ unsigned int pack_bf16(float lo, float hi) {
    union { unsigned int u; __hip_bfloat16 h[2]; } p;
    p.h[0] = __float2bfloat16(lo);
    p.h[1] = __float2bfloat16(hi);
    return p.u;
}

// ---------------------------------------------------------------------------
// Kernel 1: gather kept columns of attn_w, renormalize, write aw (output 2).
// grid = B*H*Q = 2048 blocks, 256 threads.
// ---------------------------------------------------------------------------
__global__ __launch_bounds__(256)
void k1_gather_norm(const float* __restrict__ attn_w,
                    const int* __restrict__ keep_idx,
                    float* __restrict__ aw_out)
{
    const int row = blockIdx.x;                 // (b*H + h)*Q + q
    const float* src = attn_w + (size_t)row * NN;
    float* dst = aw_out + (size_t)row * NK;

    __shared__ float vals[NK];
    __shared__ float red[256];

    float s = 0.f;
    for (int k = threadIdx.x; k < NK; k += 256) {
        float v = src[keep_idx[k]];
        vals[k] = v;
        s += v;
    }
    red[threadIdx.x] = s;
    __syncthreads();
    for (int st = 128; st > 0; st >>= 1) {
        if (threadIdx.x < st) red[threadIdx.x] += red[threadIdx.x + st];
        __syncthreads();
    }
    const float inv = 1.0f / (red[0] + 1e-6f);
    for (int k = threadIdx.x * 2; k < NK; k += 512) {
        float a = vals[k] * inv;
        float b = vals[k + 1] * inv;
        *reinterpret_cast<float2*>(&dst[k]) = make_float2(a, b);
    }
}

// ---------------------------------------------------------------------------
// Kernel 2 (v6): ctx partial GEMM via bf16 MFMA.
// grid = B*HKV*SPLITK2 = 4*8*8 = 256 blocks, 512 threads (8 waves, 8/CU).
// Wave w: mw = w&3 (M rows mw*16..+15), nh = w>>2 (d-half). K/split = 384,
// chunks of 64. A read from f32 aw (L3-hot, just written by k1), packed
// in-register (round-4-proven path).
//   B: gathered V staged transposed into LDS Vt[d][k] bf16, XOR chunk swizzle
//      us(d,cs) = d*64 + ((cs ^ (d&7))<<3), cs = 16B chunk (8 k) 0..7.
//      Coverage: unit=(d,cs) -> 128*8 = 1024 units = 2 passes x 512 threads.
// Partial: [bid][64][128] bf16, bid = ((b*8+hkv)*8 + ks).
// ---------------------------------------------------------------------------
#define SPLITK2 8
#define KPB2    (NK / SPLITK2)   /* 384 */
#define KCH     64

__global__ __launch_bounds__(512, 4)
void k2_ctx(const float* __restrict__ aw,
            const float* __restrict__ v_cache,
            const int* __restrict__ keep_idx,
            __hip_bfloat16* __restrict__ partial)
{
    const int bid = blockIdx.x;          // ((b*8+hkv)*8 + ks)
    const int ks  = bid & 7;
    const int hkv = (bid >> 3) & 7;
    const int b   = bid >> 6;
    const int tid = threadIdx.x;
    const int lane = tid & 63;
    const int w    = tid >> 6;           // wave id 0..7
    const int mw   = w & 3;              // M-group: rows mw*16..+15
    const int nh   = w >> 2;             // d-half: tiles nh*4..nh*4+3
    const int fr   = lane & 15;          // fragment row/col
    const int kg   = lane >> 4;          // k-group (8 bf16)

    __shared__ unsigned short Vt[128 * 64];   // 16 KB, swizzled [d][k]
    __shared__ int idxs[KCH];

    const int k0 = ks * KPB2;
    // A row for this lane: global aw row = (b*32 + hkv*4 + mw)*16 + fr
    const float* arow = aw + (size_t)((b * HH + hkv * GRP + mw) * QQ + fr) * NK + k0;
    const float* vb = v_cache + (size_t)(b * HKV + hkv) * NN * DD;

    f32x4 acc[4];
#pragma unroll
    for (int nt = 0; nt < 4; ++nt) acc[nt] = (f32x4){0.f, 0.f, 0.f, 0.f};

    // staging: pass p, thread t -> unit u = t + 512p; d = u&127, cs = u>>7
    const int sd  = tid & 127;
    const int sc0 = tid >> 7;            // 0..3

    for (int c = 0; c < KPB2; c += KCH) {
        __syncthreads();                       // Vt free (prev compute done)
        if (tid < KCH) idxs[tid] = keep_idx[k0 + c + tid];
        __syncthreads();                       // idxs ready

        // stage 64 gathered V rows, transposed + swizzled, bf16.
#pragma unroll
        for (int p = 0; p < 2; ++p) {
            const int cs = sc0 + 4 * p;        // 16B chunk 0..7 (k = 8cs..8cs+7)
            float v[8];
#pragma unroll
            for (int e = 0; e < 8; ++e)
                v[e] = vb[(size_t)idxs[8 * cs + e] * DD + sd];
            uint4 pk;
            pk.x = pack_bf16(v[0], v[1]);
            pk.y = pack_bf16(v[2], v[3]);
            pk.z = pack_bf16(v[4], v[5]);
            pk.w = pack_bf16(v[6], v[7]);
            const int us = sd * 64 + ((cs ^ (sd & 7)) << 3);
            *reinterpret_cast<uint4*>(&Vt[us]) = pk;
        }
        __syncthreads();                       // Vt ready

        // compute: 2 MFMA k-steps of 32, 4 N-tiles (this wave's d-half)
#pragma unroll
        for (int kc = 0; kc < 2; ++kc) {
            const float* ap = arow + c + kc * 32 + kg * 8;
            const float4 a0 = *reinterpret_cast<const float4*>(ap);
            const float4 a1 = *reinterpret_cast<const float4*>(ap + 4);
            union { bf16x8 v; unsigned int u[4]; } af;
            af.u[0] = pack_bf16(a0.x, a0.y);
            af.u[1] = pack_bf16(a0.z, a0.w);
            af.u[2] = pack_bf16(a1.x, a1.y);
            af.u[3] = pack_bf16(a1.z, a1.w);

            const int cs = kc * 4 + kg;        // 16B chunk index along k
            const int xr = (cs ^ (fr & 7)) << 3;
#pragma unroll
            for (int nt = 0; nt < 4; ++nt) {
                const int d  = (nh * 4 + nt) * 16 + fr;
                const int us = d * 64 + xr;    // (d&7) == (fr&7)
                bf16x8 bf = *reinterpret_cast<const bf16x8*>(&Vt[us]);
                acc[nt] = __builtin_amdgcn_mfma_f32_16x16x32_bf16(af.v, bf, acc[nt], 0, 0, 0);
            }
        }
    }

    // epilogue: C/D layout col=lane&15 (d within tile), row=(lane>>4)*4+reg
    __hip_bfloat16* pb = partial + (size_t)bid * (64 * DD);
#pragma unroll
    for (int nt = 0; nt < 4; ++nt) {
#pragma unroll
        for (int reg = 0; reg < 4; ++reg) {
            const int row = mw * 16 + kg * 4 + reg;
            pb[row * DD + (nh * 4 + nt) * 16 + fr] = __float2bfloat16(acc[nt][reg]);
        }
    }
}

// ---------------------------------------------------------------------------
// Kernel 3: reduce the 8 bf16 k-split partials into ctx_b[bq][i] (i=h*128+d)
// in BF16 -- the MFMA A-operand layout for k4.
// ---------------------------------------------------------------------------
__global__ __launch_bounds__(256)
void k3_reduce(const __hip_bfloat16* __restrict__ partial,
               __hip_bfloat16* __restrict__ ctxb)
{
    const int flat = blockIdx.x * 256 + threadIdx.x;   // bq*4096 + i
    const int bq = flat >> 12;
    const int i  = flat & 4095;
    const int b = bq >> 4, q = bq & 15;
    const int h = i >> 7,  d = i & 127;
    const int hkv = h >> 2, g = h & 3;
    const int r = g * 16 + q;

    const __hip_bfloat16* p = partial
        + (size_t)((b * 8 + hkv) * SPLITK2) * (64 * DD) + r * DD + d;
    float s = 0.f;
#pragma unroll
    for (int ss = 0; ss < SPLITK2; ++ss)
        s += __bfloat162float(p[(size_t)ss * (64 * DD)]);
    ctxb[flat] = __float2bfloat16(s);
}

// ---------------------------------------------------------------------------
// Kernel 4: out = ctx @ W^T via bf16 MFMA, M=64 x N=4096 x K=4096.
// grid = 128 N-tiles (32 o-cols) * 4 k-splits = 512 blocks, 256 threads.
// K/split = 1024 (8 chunks of 128). pout bf16.
// ---------------------------------------------------------------------------
#define K4SPLIT 4
#define K4LEN   (4096 / K4SPLIT)  /* 1024 */
#define KC4     128
#define LPAD    136               /* 128 + 8 ushort pad */

__global__ __launch_bounds__(256, 4)
void k4_gemm(const __hip_bfloat16* __restrict__ ctxb,
             const float* __restrict__ W,
             __hip_bfloat16* __restrict__ pout)
{
    const int nt  = blockIdx.x >> 2;   // 0..127  (o-cols nt*32 .. nt*32+31)
    const int ks  = blockIdx.x & 3;
    const int tid = threadIdx.x;
    const int lane = tid & 63;
    const int w    = tid >> 6;         // wave id: M-rows w*16 .. w*16+15

    __shared__ unsigned short Al[64][LPAD];   // ctx bf16 tile
    __shared__ unsigned short Bl[32][LPAD];   // W   bf16 tile

    f32x4 acc0 = {0.f, 0.f, 0.f, 0.f};
    f32x4 acc1 = {0.f, 0.f, 0.f, 0.f};

    const unsigned short* ctxu = reinterpret_cast<const unsigned short*>(ctxb);
    const int kbase = ks * K4LEN;
    const int fr = lane & 15;          // fragment row/col
    const int kg = lane >> 4;          // k-group (8 bf16 each)

    for (int ch = 0; ch < K4LEN / KC4; ++ch) {
        const int kb = kbase + ch * KC4;
        __syncthreads();

        // stage A: 64 rows x 128 bf16 (16B/thread x 4 passes)
        {
            const int cc = tid & 15;       // 8-ushort chunk within row
            const int r0 = tid >> 4;       // 16 rows per pass
#pragma unroll
            for (int p = 0; p < 4; ++p) {
                const int r = r0 + p * 16;
                float4 v = *reinterpret_cast<const float4*>(
                    ctxu + (size_t)r * 4096 + kb + cc * 8);
                *reinterpret_cast<float4*>(&Al[r][cc * 8]) = v;
            }
        }
        // stage B: 32 rows x 128 f32 -> bf16 (float4/thread x 4 passes)
        {
            const int cc = tid & 31;       // float4 col
            const int r0 = tid >> 5;       // 8 rows per pass
#pragma unroll
            for (int p = 0; p < 4; ++p) {
                const int r = r0 + p * 8;
                float4 v = *reinterpret_cast<const float4*>(
                    W + (size_t)(nt * 32 + r) * 4096 + kb + cc * 4);
                union { ushort4 u; __hip_bfloat16 h[4]; } pk;
                pk.h[0] = __float2bfloat16(v.x);
                pk.h[1] = __float2bfloat16(v.y);
                pk.h[2] = __float2bfloat16(v.z);
                pk.h[3] = __float2bfloat16(v.w);
                *reinterpret_cast<ushort4*>(&Bl[r][cc * 4]) = pk.u;
            }
        }
        __syncthreads();

#pragma unroll
        for (int kst = 0; kst < KC4 / 32; ++kst) {
            const int ko = kst * 32 + kg * 8;
            bf16x8 a  = *reinterpret_cast<const bf16x8*>(&Al[w * 16 + fr][ko]);
            bf16x8 b0 = *reinterpret_cast<const bf16x8*>(&Bl[fr][ko]);
            bf16x8 b1 = *reinterpret_cast<const bf16x8*>(&Bl[16 + fr][ko]);
            acc0 = __builtin_amdgcn_mfma_f32_16x16x32_bf16(a, b0, acc0, 0, 0, 0);
            acc1 = __builtin_amdgcn_mfma_f32_16x16x32_bf16(a, b1, acc1, 0, 0, 0);
        }
    }

    // epilogue: C/D layout col=lane&15, row=(lane>>4)*4+reg
    __hip_bfloat16* pb = pout + (size_t)ks * (64 * 4096);
#pragma unroll
    for (int reg = 0; reg < 4; ++reg) {
        const int row = w * 16 + kg * 4 + reg;
        pb[(size_t)row * 4096 + nt * 32 + fr]      = __float2bfloat16(acc0[reg]);
        pb[(size_t)row * 4096 + nt * 32 + 16 + fr] = __float2bfloat16(acc1[reg]);
    }
}

// ---------------------------------------------------------------------------
// Kernel 5: reduce the 4 bf16 k-split output partials -> out (output 1).
// ---------------------------------------------------------------------------
__global__ __launch_bounds__(256)
void k5_out(const __hip_bfloat16* __restrict__ pout, float* __restrict__ out)
{
    const int flat = blockIdx.x * 256 + threadIdx.x;
    float s = 0.f;
#pragma unroll
    for (int ss = 0; ss < K4SPLIT; ++ss)
        s += __bfloat162float(pout[(size_t)ss * (64 * 4096) + flat]);
    out[flat] = s;
}

// ---------------------------------------------------------------------------
extern "C" void kernel_launch(void* const* d_in, const int* in_sizes, int n_in,
                              void* d_out, int out_size, void* d_ws, size_t ws_size,
                              hipStream_t stream)
{
    const float* attn_w  = (const float*)d_in[0];   // [4][32][16][4096]
    const float* v_cache = (const float*)d_in[1];   // [4][8][4096][128]
    const float* o_proj  = (const float*)d_in[2];   // [4096][4096]
    const int*   keep_idx = (const int*)d_in[3];    // [3072]

    float* out    = (float*)d_out;                  // [4][16][4096] = 262144
    float* aw_out = (float*)d_out + 262144;         // [4][32][16][3072] = 6291456

    // ws layout (bytes):
    //   [0, 4 MB)       : k2 bf16 partial (2,097,152 bf16) -- dead after k3
    //   [0, 2 MB)       : k4 bf16 pout (1,048,576 bf16)    -- reuses region
    //   [8 MB, 8.5 MB)  : ctx bf16 (262,144 bf16)
    __hip_bfloat16* partial2 = (__hip_bfloat16*)d_ws;
    __hip_bfloat16* ctxb = (__hip_bfloat16*)((char*)d_ws + (size_t)8 * 1024 * 1024);
    __hip_bfloat16* pout = (__hip_bfloat16*)d_ws;

    k1_gather_norm<<<BB * HH * QQ, 256, 0, stream>>>(attn_w, keep_idx, aw_out);
    k2_ctx<<<BB * HKV * SPLITK2, 512, 0, stream>>>(aw_out, v_cache, keep_idx, partial2);
    k3_reduce<<<(64 * 4096) / 256, 256, 0, stream>>>(partial2, ctxb);
    k4_gemm<<<128 * K4SPLIT, 256, 0, stream>>>(ctxb, o_proj, pout);
    k5_out<<<(64 * 4096) / 256, 256, 0, stream>>>(pout, out);
}